// Round 11
// baseline (123.197 us; speedup 1.0000x reference)
//
#include <hip/hip_runtime.h>
#include <hip/hip_bf16.h>

// VectorQuantizer: x [32768 x 64] fp32, e [64 x 1024] fp32.
// d_out = [out (2097152 f32) = x + (q-x), loss = 1.25*mean((q-x)^2)].
//
// R11: main resized so the live set FITS the allocator's 128-reg operating
// point (the R4 shape's ~200-reg set spilled at every occupancy R3-R10):
// block = 32 rows (2 M-tiles/wave), ring-2 B prefetch, grid 1024 = 4 blk/CU,
// amdgpu_waves_per_eu(4,4) -> 4 waves/SIMD, est. ~118 VGPR, zero spill.
// Candidate reduce parallelized (8 thr/row + shfl). Numerics identical to
// the validated path: 6-MFMA bf16x3-split keys se-2dot, MARGIN flag list,
// R9's parallel exact-fp32 vq_fix (R1-validated math), ticket loss finalize.

#define NROWS 32768
#define DDIM  64
#define KCODE 1024
#define NELEM (NROWS * DDIM)
#define MARGIN 2.5e-4f
#define FIXBLOCKS 256

typedef __attribute__((ext_vector_type(8))) short bf16x8;
typedef __attribute__((ext_vector_type(4))) float f32x4;

static __device__ __forceinline__ unsigned short f2bf(float v) {
    __hip_bfloat16 h = __float2bfloat16(v);
    unsigned short b;
    __builtin_memcpy(&b, &h, 2);
    return b;
}
static __device__ __forceinline__ float bf2f(unsigned short b) {
    unsigned int u = ((unsigned int)b) << 16;
    float f;
    __builtin_memcpy(&f, &u, 4);
    return f;
}

// ---------------------------------------------------------------------------
// prep (64 blocks x 256): per block 16 codes. se[k] exact fp32 (ascending-d
// fmaf — must match vq_fix), eT[k][d] fp32, ehT/elT[k][d] bf16 hi/lo.
__global__ void vq_prep(const float* __restrict__ e,
                        float* __restrict__ se,
                        float* __restrict__ eT,
                        unsigned short* __restrict__ ehT,
                        unsigned short* __restrict__ elT,
                        int* __restrict__ ctrl) {
    __shared__ float tile[64][17];
    const int t = threadIdx.x;
    const int k0 = blockIdx.x * 16;
    if (blockIdx.x == 0 && t < 4) ctrl[t] = 0;
    #pragma unroll
    for (int i = 0; i < 4; ++i) {
        int idx = i * 256 + t;
        int d = idx >> 4, kk = idx & 15;
        tile[d][kk] = e[d * KCODE + k0 + kk];
    }
    __syncthreads();
    if (t < 16) {
        float s = 0.f;
        #pragma unroll
        for (int d = 0; d < 64; ++d) { float v = tile[d][t]; s = fmaf(v, v, s); }
        se[k0 + t] = s;
    }
    const int kk = t >> 4;           // code 0..15
    const int dg = (t & 15) * 4;     // dim chunk
    float v0 = tile[dg + 0][kk], v1 = tile[dg + 1][kk];
    float v2 = tile[dg + 2][kk], v3 = tile[dg + 3][kk];
    *(float4*)&eT[(size_t)(k0 + kk) * 64 + dg] = make_float4(v0, v1, v2, v3);
    unsigned short h0 = f2bf(v0), h1 = f2bf(v1), h2 = f2bf(v2), h3 = f2bf(v3);
    *(ushort4*)&ehT[(size_t)(k0 + kk) * 64 + dg] = make_ushort4(h0, h1, h2, h3);
    *(ushort4*)&elT[(size_t)(k0 + kk) * 64 + dg] =
        make_ushort4(f2bf(v0 - bf2f(h0)), f2bf(v1 - bf2f(h1)),
                     f2bf(v2 - bf2f(h2)), f2bf(v3 - bf2f(h3)));
}

// ---------------------------------------------------------------------------
__attribute__((amdgpu_waves_per_eu(4, 4)))
__launch_bounds__(256)
__global__ void vq_main(const float* __restrict__ x,
                        const float* __restrict__ se,
                        const float* __restrict__ eT,
                        const unsigned short* __restrict__ ehT,
                        const unsigned short* __restrict__ elT,
                        float* __restrict__ out,
                        float* __restrict__ lossAcc,
                        int* __restrict__ cnt,
                        int2* __restrict__ list) {
    __shared__ float Lb [32][65];
    __shared__ float Lb2[32][65];
    __shared__ int   Li [32][65];
    __shared__ int   rowIdx[32];
    __shared__ float wsum[4];

    const int t = threadIdx.x;
    const int lane = t & 63;
    const int w = t >> 6;                 // 0..3, this wave's K-slice
    const int quad = lane >> 4, l15 = lane & 15;
    const int rowBlk = blockIdx.x * 32;

    // ---- A fragments: 2 M-tiles (rows rowBlk..rowBlk+31), in-register ----
    bf16x8 ah[2][2], al[2][2];
    #pragma unroll
    for (int mt = 0; mt < 2; ++mt) {
        #pragma unroll
        for (int ks = 0; ks < 2; ++ks) {
            const float4* ap = (const float4*)(x + (size_t)(rowBlk + mt * 16 + l15) * 64
                                               + ks * 32 + quad * 8);
            float4 a0 = ap[0], a1 = ap[1];
            float av[8] = {a0.x, a0.y, a0.z, a0.w, a1.x, a1.y, a1.z, a1.w};
            bf16x8 h, l;
            #pragma unroll
            for (int j = 0; j < 8; ++j) {
                unsigned short hb = f2bf(av[j]);
                h[j] = (short)hb;
                l[j] = (short)f2bf(av[j] - bf2f(hb));
            }
            ah[mt][ks] = h; al[mt][ks] = l;
        }
    }

    float sb[2][4], sb2[2][4];
    int   si[2][4];
    #pragma unroll
    for (int mt = 0; mt < 2; ++mt)
        #pragma unroll
        for (int r = 0; r < 4; ++r) { sb[mt][r] = 3.4e38f; sb2[mt][r] = 3.4e38f; si[mt][r] = 0; }

    // ---- B ring-2 register prefetch over this wave's 256 codes (16 tiles) ----
    const int cbase = w * 256;
    bf16x8 h0[2], h1[2], l0[2], l1[2];
    float sen[2];
    #pragma unroll
    for (int p = 0; p < 2; ++p) {
        const int nl = cbase + p * 16 + l15;
        const bf16x8* hp = (const bf16x8*)(ehT + (size_t)nl * 64 + quad * 8);
        const bf16x8* lp = (const bf16x8*)(elT + (size_t)nl * 64 + quad * 8);
        h0[p] = hp[0]; h1[p] = hp[4]; l0[p] = lp[0]; l1[p] = lp[4];
        sen[p] = se[nl];
    }

    #pragma unroll 2
    for (int nt = 0; nt < 16; ++nt) {
        const int p = nt & 1;
        bf16x8 ch0 = h0[p], ch1 = h1[p], cl0 = l0[p], cl1 = l1[p];
        float cse = sen[p];
        {   // prefetch tile nt+2 (tail reads land in the 64-code ws pad)
            const int nl = cbase + (nt + 2) * 16 + l15;
            const bf16x8* hp = (const bf16x8*)(ehT + (size_t)nl * 64 + quad * 8);
            const bf16x8* lp = (const bf16x8*)(elT + (size_t)nl * 64 + quad * 8);
            h0[p] = hp[0]; h1[p] = hp[4]; l0[p] = lp[0]; l1[p] = lp[4];
            sen[p] = se[nl];
        }
        const int nl = cbase + nt * 16 + l15;
        #pragma unroll
        for (int mt = 0; mt < 2; ++mt) {
            f32x4 aA = {0.f, 0.f, 0.f, 0.f}, aB = {0.f, 0.f, 0.f, 0.f};
            aA = __builtin_amdgcn_mfma_f32_16x16x32_bf16(ah[mt][0], ch0, aA, 0, 0, 0);
            aB = __builtin_amdgcn_mfma_f32_16x16x32_bf16(ah[mt][1], ch1, aB, 0, 0, 0);
            aA = __builtin_amdgcn_mfma_f32_16x16x32_bf16(ah[mt][0], cl0, aA, 0, 0, 0);
            aB = __builtin_amdgcn_mfma_f32_16x16x32_bf16(ah[mt][1], cl1, aB, 0, 0, 0);
            aA = __builtin_amdgcn_mfma_f32_16x16x32_bf16(al[mt][0], ch0, aA, 0, 0, 0);
            aB = __builtin_amdgcn_mfma_f32_16x16x32_bf16(al[mt][1], ch1, aB, 0, 0, 0);
            #pragma unroll
            for (int r = 0; r < 4; ++r) {
                float key = fmaf(-2.f, aA[r] + aB[r], cse);   // se - 2*dot
                bool lt = key < sb[mt][r];                     // strict: earliest k wins
                sb2[mt][r] = fminf(sb2[mt][r], fmaxf(sb[mt][r], key));
                sb[mt][r]  = fminf(sb[mt][r], key);
                si[mt][r]  = lt ? nl : si[mt][r];
            }
        }
    }

    // ---- exchange candidates: row-local = mt*16+quad*4+r, col = w*16+l15 ----
    const int col = w * 16 + l15;
    #pragma unroll
    for (int mt = 0; mt < 2; ++mt)
        #pragma unroll
        for (int r = 0; r < 4; ++r) {
            int rr = mt * 16 + quad * 4 + r;
            Lb [rr][col] = sb [mt][r];
            Lb2[rr][col] = sb2[mt][r];
            Li [rr][col] = si [mt][r];
        }
    __syncthreads();

    // ---- parallel per-row reduce: 8 threads per row, 8 cols each + shfl ----
    {
        const int r = t >> 3, seg = t & 7;
        const int c0 = seg * 8;
        float B = Lb[r][c0], B2 = Lb2[r][c0];
        int   I = Li[r][c0];
        #pragma unroll
        for (int c = 1; c < 8; ++c) {
            float b = Lb[r][c0 + c], b2 = Lb2[r][c0 + c];
            int i = Li[r][c0 + c];
            float nB2 = fminf(fminf(B2, b2), fmaxf(B, b));
            bool take = (b < B) || (b == B && i < I);
            B = take ? b : B;
            I = take ? i : I;
            B2 = nB2;
        }
        #pragma unroll
        for (int m = 1; m < 8; m <<= 1) {
            float ob  = __shfl_xor(B,  m, 64);
            float ob2 = __shfl_xor(B2, m, 64);
            int   oi  = __shfl_xor(I,  m, 64);
            float nB2 = fminf(fminf(B2, ob2), fmaxf(B, ob));
            bool take = (ob < B) || (ob == B && oi < I);
            B = take ? ob : B;
            I = take ? oi : I;
            B2 = nB2;
        }
        if (seg == 0) {
            rowIdx[r] = I;
            if (B2 - B < MARGIN) {
                int p = atomicAdd(cnt, 1);
                list[p] = make_int2(rowBlk + r, I);
            }
        }
    }
    __syncthreads();

    // ---- epilogue: thread t handles row t>>3, elems [(t&7)*8, +8) ----
    {
        const int r = t >> 3, c = (t & 7) * 8;
        const int idx = rowIdx[r];
        const float4* qrow = (const float4*)(eT + (size_t)idx * 64 + c);
        const float4* xrow = (const float4*)(x + (size_t)(rowBlk + r) * 64 + c);
        float4* orow = (float4*)(out + (size_t)(rowBlk + r) * 64 + c);
        float lsum = 0.f;
        #pragma unroll
        for (int i = 0; i < 2; ++i) {
            float4 q = qrow[i];
            float4 xv = xrow[i];
            float4 o;
            float dx;
            dx = q.x - xv.x; o.x = xv.x + dx; lsum = fmaf(dx, dx, lsum);
            dx = q.y - xv.y; o.y = xv.y + dx; lsum = fmaf(dx, dx, lsum);
            dx = q.z - xv.z; o.z = xv.z + dx; lsum = fmaf(dx, dx, lsum);
            dx = q.w - xv.w; o.w = xv.w + dx; lsum = fmaf(dx, dx, lsum);
            orow[i] = o;
        }
        #pragma unroll
        for (int off = 32; off > 0; off >>= 1)
            lsum += __shfl_down(lsum, off, 64);
        if (lane == 0) wsum[w] = lsum;
    }
    __syncthreads();
    if (t == 0)
        atomicAdd(lossAcc, wsum[0] + wsum[1] + wsum[2] + wsum[3]);
}

// ---------------------------------------------------------------------------
// Fast exact fp32 re-score of flagged rows (R9, validated). One block per
// flagged row (grid-stride); 4 interleaved independent fmaf chains/thread
// (ascending-d per chain == R1-validated math); parallel argmin reduce.
__launch_bounds__(256)
__global__ void vq_fix(const float* __restrict__ x,
                       const float* __restrict__ se,
                       const float* __restrict__ eT,
                       const int2* __restrict__ list,
                       const int* __restrict__ cnt,
                       float* __restrict__ lossAcc,
                       int* __restrict__ done,
                       float* __restrict__ out) {
    __shared__ float xs[64];
    __shared__ float cb[256];
    __shared__ int   ci[256];
    __shared__ int   newIdxS;
    const int t = threadIdx.x;
    const int n = *cnt;

    for (int i = blockIdx.x; i < n; i += gridDim.x) {
        int2 en = list[i];
        const int row = en.x, oldIdx = en.y;
        if (t < 64) xs[t] = x[(size_t)row * 64 + t];
        __syncthreads();

        float sx = 0.f;
        #pragma unroll
        for (int d = 0; d < 64; ++d) sx = fmaf(xs[d], xs[d], sx);

        const int k0 = t * 4;
        const float4* e0 = (const float4*)(eT + (size_t)(k0 + 0) * 64);
        const float4* e1 = (const float4*)(eT + (size_t)(k0 + 1) * 64);
        const float4* e2 = (const float4*)(eT + (size_t)(k0 + 2) * 64);
        const float4* e3 = (const float4*)(eT + (size_t)(k0 + 3) * 64);
        float dot0 = 0.f, dot1 = 0.f, dot2 = 0.f, dot3 = 0.f;
        #pragma unroll
        for (int i4 = 0; i4 < 16; ++i4) {
            float4 v0 = e0[i4], v1 = e1[i4], v2 = e2[i4], v3 = e3[i4];
            float xa = xs[4 * i4 + 0], xb = xs[4 * i4 + 1];
            float xc = xs[4 * i4 + 2], xd = xs[4 * i4 + 3];
            dot0 = fmaf(xa, v0.x, dot0); dot0 = fmaf(xb, v0.y, dot0);
            dot0 = fmaf(xc, v0.z, dot0); dot0 = fmaf(xd, v0.w, dot0);
            dot1 = fmaf(xa, v1.x, dot1); dot1 = fmaf(xb, v1.y, dot1);
            dot1 = fmaf(xc, v1.z, dot1); dot1 = fmaf(xd, v1.w, dot1);
            dot2 = fmaf(xa, v2.x, dot2); dot2 = fmaf(xb, v2.y, dot2);
            dot2 = fmaf(xc, v2.z, dot2); dot2 = fmaf(xd, v2.w, dot2);
            dot3 = fmaf(xa, v3.x, dot3); dot3 = fmaf(xb, v3.y, dot3);
            dot3 = fmaf(xc, v3.z, dot3); dot3 = fmaf(xd, v3.w, dot3);
        }
        float dd0 = (sx + se[k0 + 0]) - 2.0f * dot0;
        float dd1 = (sx + se[k0 + 1]) - 2.0f * dot1;
        float dd2 = (sx + se[k0 + 2]) - 2.0f * dot2;
        float dd3 = (sx + se[k0 + 3]) - 2.0f * dot3;
        float db = dd0; int di = k0;
        if (dd1 < db) { db = dd1; di = k0 + 1; }
        if (dd2 < db) { db = dd2; di = k0 + 2; }
        if (dd3 < db) { db = dd3; di = k0 + 3; }
        cb[t] = db; ci[t] = di;
        __syncthreads();

        if (t < 64) {
            float B = cb[t]; int I = ci[t];
            #pragma unroll
            for (int s = 64; s < 256; s += 64) {
                float b = cb[t + s]; int i2 = ci[t + s];
                bool take = (b < B) || (b == B && i2 < I);
                B = take ? b : B;
                I = take ? i2 : I;
            }
            #pragma unroll
            for (int m = 1; m < 64; m <<= 1) {
                float ob = __shfl_xor(B, m, 64);
                int   oi = __shfl_xor(I, m, 64);
                bool take = (ob < B) || (ob == B && oi < I);
                B = take ? ob : B;
                I = take ? oi : I;
            }
            if (t == 0) newIdxS = I;
        }
        __syncthreads();

        const int ni = newIdxS;
        if (ni != oldIdx) {
            if (t < 64) {
                float xv = xs[t];
                float qn = eT[(size_t)ni * 64 + t];
                float qo = eT[(size_t)oldIdx * 64 + t];
                float dn = qn - xv, dl = qo - xv;
                out[(size_t)row * 64 + t] = xv + dn;
                float delta = dn * dn - dl * dl;
                #pragma unroll
                for (int off = 32; off > 0; off >>= 1)
                    delta += __shfl_down(delta, off, 64);
                if (t == 0) atomicAdd(lossAcc, delta);
            }
        }
        __syncthreads();
    }

    if (t == 0) {
        __threadfence();
        int fin = atomicAdd(done, 1);
        if (fin == FIXBLOCKS - 1) {
            float s = atomicAdd(lossAcc, 0.0f);   // coherent read of final sum
            float m = s / (float)NELEM;
            out[NELEM] = 0.25f * m + m;
        }
    }
}

// ---------------------------------------------------------------------------
extern "C" void kernel_launch(void* const* d_in, const int* in_sizes, int n_in,
                              void* d_out, int out_size, void* d_ws, size_t ws_size,
                              hipStream_t stream) {
    const float* x = (const float*)d_in[0];
    const float* e = (const float*)d_in[1];
    float* out = (float*)d_out;
    float* ws  = (float*)d_ws;

    // ws layout (float offsets) — identical to R4/R9/R10:
    //   [0..15]   ctrl: lossAcc, cnt, done, spare
    //   +64       se   [1088 used (64-code read pad); region to +1280]
    //   +1280     eT   [65536]
    //   +66816    ehT  [1088*64 ushort = 34816 f]
    //   +101632   elT  [1088*64 ushort = 34816 f]
    //   +136448   list [32768 int2 = 65536 f]
    float* lossAcc      = ws;
    int*   cnt          = (int*)(ws + 1);
    int*   done         = (int*)(ws + 2);
    float* se           = ws + 64;
    float* eT           = ws + 1280;
    unsigned short* ehT = (unsigned short*)(ws + 66816);
    unsigned short* elT = (unsigned short*)(ws + 101632);
    int2*  list         = (int2*)(ws + 136448);

    vq_prep<<<64, 256, 0, stream>>>(e, se, eT, ehT, elT, (int*)ws);
    vq_main<<<NROWS / 32, 256, 0, stream>>>(x, se, eT, ehT, elT, out, lossAcc, cnt, list);
    vq_fix<<<FIXBLOCKS, 256, 0, stream>>>(x, se, eT, list, cnt, lossAcc, done, out);
}